// Round 5
// baseline (354.511 us; speedup 1.0000x reference)
//
#include <hip/hip_runtime.h>
#include <hip/hip_fp16.h>

// Problem: B=8192, L=64, M=64, LOCAL_DIM=4, eps shape (4, 64, 64, 65, 65) f32.
// out[b] = sum_m prod_l eps[idx[b,l], m, l, nup[b,l], ndn[b,l]]
// nup/ndn = exclusive cumsum of bit0/bit1 of idx along l.
//
// eps element strides: d:17305600, m:270400, l:4225, u:65, n:1
// Compact transposed table (reachable u<=l, n<=l states), fp16:
//   tab[(P_l + u*(l+1) + n)*256 + d*64 + m],  P_l = l(l+1)(2l+1)/6
// fp16 accuracy: eps ~[0.7,1.3]; product-of-64 rel err ~2.3e-3; absmax 0.5
// observed vs 1.56 threshold.
//
// R4: only transpose states actually VISITED (per-l [umin,umax]x[nmin,nmax]
// pre-pass). ~3.5x less transpose traffic.
// R5: main = 4 batches/wave, ushort4 gathers, packed-index shuffle. (341.8us)
// R6: FAILED - cooperative fusion serialized the transpose. Reverted.
//     But it measured: restores+gaps ~= 132us, so chain ~= 38us at R7.
// R7: 4-kernel chain + ballot/popcount ranges. (335.9us)
// R8: ranges@512 blocks + unrolled loads; main 8 batches/wave (ushort8).
//     Bench ABORTED with no HIP error; audit shows all addresses are
//     data-independently in-bounds & 16B-aligned, and the run's harness
//     timing was pathological (push_in_npz 2721s vs ~0 normally) ->
//     diagnosed infra flake, NOT a kernel fault.
// R9 (this round): resubmit R8 unchanged. If it aborts again on a healthy
//     run, bisect by reverting main to R5 while keeping ranges@512.
// Budget: fill 166 (harness, fixed) + restores/gaps 132 (harness, fixed)
//         + chain ~30 -> predict ~328us.

#define TAB_HALF_BYTES ((size_t)89440 * 256 * 2)

typedef unsigned short ushort8 __attribute__((ext_vector_type(8)));

__global__ __launch_bounds__(256) void seggps_init(int* __restrict__ ranges) {
  int t = threadIdx.x;
  if (t < 64) {
    ranges[t] = 64;        // umin
    ranges[64 + t] = -1;   // umax
    ranges[128 + t] = 64;  // nmin
    ranges[192 + t] = -1;  // nmax
  }
}

// grid = 512 blocks x 256 thr; block handles 16 batches (4 per wave,
// loads unrolled so all 4 issue before the first ballot). Ballot+popcount
// gives each batch's exclusive (u,n) at every site; LDS min/max then 256
// global atomics per block.
__global__ __launch_bounds__(256) void seggps_ranges(
    const int* __restrict__ indices, int* __restrict__ ranges) {
  __shared__ int s_umin[64], s_umax[64], s_nmin[64], s_nmax[64];
  int t = threadIdx.x;
  if (t < 64) { s_umin[t] = 64; s_umax[t] = -1; s_nmin[t] = 64; s_nmax[t] = -1; }
  __syncthreads();
  int wave = t >> 6, lane = t & 63;    // lane = l
  unsigned long long ltmask =
      (lane == 63) ? 0x7fffffffffffffffull : ((1ull << lane) - 1ull);
  int vv[4];
#pragma unroll
  for (int i = 0; i < 4; ++i) {
    int b = blockIdx.x * 16 + wave * 4 + i;
    vv[i] = indices[b * 64 + lane];
  }
#pragma unroll
  for (int i = 0; i < 4; ++i) {
    int v = vv[i];
    unsigned long long m0 = __ballot(v & 1);   // bit l set iff site l has up
    unsigned long long m1 = __ballot(v & 2);
    int eu = __popcll(m0 & ltmask);            // exclusive cumsum at site lane
    int ed = __popcll(m1 & ltmask);
    atomicMin(&s_umin[lane], eu); atomicMax(&s_umax[lane], eu);
    atomicMin(&s_nmin[lane], ed); atomicMax(&s_nmax[lane], ed);
  }
  __syncthreads();
  if (t < 64) {
    atomicMin(&ranges[t], s_umin[t]);
    atomicMax(&ranges[64 + t], s_umax[t]);
    atomicMin(&ranges[128 + t], s_nmin[t]);
    atomicMax(&ranges[192 + t], s_nmax[t]);
  }
}

__global__ __launch_bounds__(256) void seggps_transpose(
    const float* __restrict__ eps, __half* __restrict__ tab,
    const int* __restrict__ ranges) {
  int bid = blockIdx.x;                 // grid = 4 * 2080 (triangular)
  int d = bid / 2080;
  int t = bid % 2080;
  int l = (int)((sqrtf(8.0f * (float)t + 1.0f) - 1.0f) * 0.5f);
  while ((l + 1) * (l + 2) / 2 <= t) ++l;   // fix fp rounding
  while (l * (l + 1) / 2 > t) --l;
  int u = t - l * (l + 1) / 2;

  int umin = ranges[l], umax = ranges[64 + l];
  if (u < umin || u > umax) return;     // no batch visits this u at site l
  int nmin = ranges[128 + l], nmax = ranges[192 + l];  // nmax <= l always

  int lane = threadIdx.x & 63;          // n on load, m on store
  int wave = threadIdx.x >> 6;          // 4 waves

  __shared__ float tile[64][65];        // [m][n]

  // load: coalesced along n (stride 1 in eps); nontemporal (no reuse,
  // eps = 277MB > L3)
  const float* src = eps + ((size_t)(d * 64) * 64 + l) * 4225 + u * 65;
  if (lane >= nmin && lane <= nmax) {
#pragma unroll 4
    for (int m = wave; m < 64; m += 4) {
      tile[m][lane] = __builtin_nontemporal_load(&src[(size_t)m * 270400 + lane]);
    }
  }
  __syncthreads();

  // store: coalesced along m (128B contiguous per wave)
  int Pl = l * (l + 1) * (2 * l + 1) / 6;
  __half* dst = tab + (size_t)(Pl + u * (l + 1)) * 256 + d * 64 + lane;
  for (int n = nmin + wave; n <= nmax; n += 4) {
    dst[n * 256] = __float2half(tile[lane][n]);
  }
}

// R8 main: 8 batches per wave. g = lane>>3 selects the batch, Lm = lane&7
// selects an m-octet (m = 8*Lm .. 8*Lm+7, ushort8 = 16B load; 8 lanes x 16B
// = one 128B line per batch-group per site, 8 groups = 1KB per wave-load).
// Indices of the 8 batches packed 2 bits each -> one __shfl per site.
// Safety: v masked to [0,3]; up,dn <= l (increment <=1/iter) so
// o < 89440*256 and o*2+16 <= TAB_HALF_BYTES, data-independently.
__global__ __launch_bounds__(256, 4) void seggps_main(
    const int* __restrict__ indices, const __half* __restrict__ tab,
    float* __restrict__ out) {
  int wave = threadIdx.x >> 6;
  int lane = threadIdx.x & 63;
  int g = lane >> 3;                    // batch subgroup 0..7
  int Lm = lane & 7;                    // m-octet index
  int b0 = (blockIdx.x * 4 + wave) * 8; // this wave handles b0 .. b0+7

  int ipk = 0;
#pragma unroll
  for (int j = 0; j < 8; ++j) {
    ipk |= indices[(b0 + j) * 64 + lane] << (2 * j);
  }

  float p0 = 1.f, p1 = 1.f, p2 = 1.f, p3 = 1.f;
  float p4 = 1.f, p5 = 1.f, p6 = 1.f, p7 = 1.f;
  int up = 0, dn = 0;                   // this lane's batch's counters
  int Pl = 0;                           // l(l+1)(2l+1)/6, built incrementally
  int mbase = Lm * 8;
#pragma unroll 16
  for (int l = 0; l < 64; ++l) {
    int s = __shfl(ipk, l, 64);
    int v = (s >> (2 * g)) & 3;
    int o = (Pl + up * (l + 1) + dn) * 256 + v * 64 + mbase;
    ushort8 q = *reinterpret_cast<const ushort8*>(tab + o);  // 16B, aligned
    p0 *= __half2float(__ushort_as_half(q[0]));
    p1 *= __half2float(__ushort_as_half(q[1]));
    p2 *= __half2float(__ushort_as_half(q[2]));
    p3 *= __half2float(__ushort_as_half(q[3]));
    p4 *= __half2float(__ushort_as_half(q[4]));
    p5 *= __half2float(__ushort_as_half(q[5]));
    p6 *= __half2float(__ushort_as_half(q[6]));
    p7 *= __half2float(__ushort_as_half(q[7]));
    up += v & 1;
    dn += (v >> 1) & 1;
    Pl += (l + 1) * (l + 1);
  }
  // p0..p7 are products for eight DIFFERENT m -> sum, then reduce over the
  // 8-lane group (width=8 keeps the shuffle inside the group).
  float r = ((p0 + p1) + (p2 + p3)) + ((p4 + p5) + (p6 + p7));
#pragma unroll
  for (int s = 4; s; s >>= 1) r += __shfl_down(r, s, 8);
  if (Lm == 0) out[b0 + g] = r;
}

// Fallback if workspace is too small: gather straight from eps.
__global__ __launch_bounds__(256) void seggps_direct(
    const int* __restrict__ indices, const float* __restrict__ eps,
    float* __restrict__ out) {
  int wave = threadIdx.x >> 6;
  int lane = threadIdx.x & 63;          // lane = m
  int b = blockIdx.x * 4 + wave;

  int myidx = indices[b * 64 + lane];

  float p0 = 1.f, p1 = 1.f, p2 = 1.f, p3 = 1.f;
  int up = 0, dn = 0;
#pragma unroll 8
  for (int l = 0; l < 64; ++l) {
    int v = __shfl(myidx, l, 64);
    size_t off = ((size_t)((v * 64 + lane) * 64 + l)) * 4225 + up * 65 + dn;
    float e = eps[off];
    if ((l & 3) == 0)      p0 *= e;
    else if ((l & 3) == 1) p1 *= e;
    else if ((l & 3) == 2) p2 *= e;
    else                   p3 *= e;
    up += v & 1;
    dn += (v >> 1) & 1;
  }
  float p = (p0 * p1) * (p2 * p3);
#pragma unroll
  for (int s = 32; s; s >>= 1) p += __shfl_down(p, s, 64);
  if (lane == 0) out[b] = p;
}

extern "C" void kernel_launch(void* const* d_in, const int* in_sizes, int n_in,
                              void* d_out, int out_size, void* d_ws, size_t ws_size,
                              hipStream_t stream) {
  const int* indices = (const int*)d_in[0];   // (8192, 64) int
  const float* eps   = (const float*)d_in[1]; // (4, 64, 64, 65, 65) f32
  float* out = (float*)d_out;                 // (8192,) f32

  if (ws_size >= TAB_HALF_BYTES + 1024) {
    __half* tab = (__half*)d_ws;
    int* ranges = (int*)((char*)d_ws + TAB_HALF_BYTES);  // 256 ints
    hipLaunchKernelGGL(seggps_init, dim3(1), dim3(256), 0, stream, ranges);
    hipLaunchKernelGGL(seggps_ranges, dim3(512), dim3(256), 0, stream,
                       indices, ranges);
    hipLaunchKernelGGL(seggps_transpose, dim3(4 * 2080), dim3(256), 0, stream,
                       eps, tab, ranges);
    hipLaunchKernelGGL(seggps_main, dim3(8192 / 32), dim3(256), 0, stream,
                       indices, tab, out);
  } else {
    hipLaunchKernelGGL(seggps_direct, dim3(8192 / 4), dim3(256), 0, stream,
                       indices, eps, out);
  }
}

// Round 7
// 337.244 us; speedup vs baseline: 1.0512x; 1.0512x over previous
//
#include <hip/hip_runtime.h>
#include <hip/hip_fp16.h>

// Problem: B=8192, L=64, M=64, LOCAL_DIM=4, eps shape (4, 64, 64, 65, 65) f32.
// out[b] = sum_m prod_l eps[idx[b,l], m, l, nup[b,l], ndn[b,l]]
// nup/ndn = exclusive cumsum of bit0/bit1 of idx along l.
//
// eps element strides: d:17305600, m:270400, l:4225, u:65, n:1
// Compact transposed table (reachable u<=l, n<=l states), fp16:
//   tab[(P_l + u*(l+1) + n)*256 + d*64 + m],  P_l = l(l+1)(2l+1)/6
// fp16 accuracy: eps ~[0.7,1.3]; product-of-64 rel err ~2.3e-3; absmax 0.5
// observed vs 1.56 threshold.
//
// History:
// R4: visited-state-only transpose (per-l range pre-pass). ~3.5x less traffic.
// R5: main = 4 batches/wave, ushort4 gathers, packed-index shuffle. (341.8us)
// R6: FAILED - cooperative fusion serialized the transpose (500us).
//     Measured: harness restores+gaps ~= 132us.
// R7: 4-kernel chain + ballot/popcount ranges @128 blocks. (335.9us, BEST)
// R8/R9: ranges@512 + 8-batch ushort8 main -> 354.5us REGRESSION
//     (atomic contention x4 in ranges; 8 scattered 128B segments per
//     wave-load in main). Reverted.
// R10: exact R7 configuration restored -> infra failure ("container failed
//      twice"), no measurement. R11 (this round): resubmit unchanged.
//
// Floor arithmetic: harness poison-fill 166us (1.08GB @83% peak, fixed) +
// harness restore/gaps ~132us (fixed) + chain ~38us (memory floor ~22us,
// remainder below run-to-run noise) ~= 336us = R7's measurement.

#define TAB_HALF_BYTES ((size_t)89440 * 256 * 2)

__global__ __launch_bounds__(256) void seggps_init(int* __restrict__ ranges) {
  int t = threadIdx.x;
  if (t < 64) {
    ranges[t] = 64;        // umin
    ranges[64 + t] = -1;   // umax
    ranges[128 + t] = 64;  // nmin
    ranges[192 + t] = -1;  // nmax
  }
}

// grid = 128 blocks x 256 thr; block handles 64 batches. Ballot+popcount
// gives each batch's exclusive (u,n) at every site; LDS min/max then 256
// global atomics per block.
__global__ __launch_bounds__(256) void seggps_ranges(
    const int* __restrict__ indices, int* __restrict__ ranges) {
  __shared__ int s_umin[64], s_umax[64], s_nmin[64], s_nmax[64];
  int t = threadIdx.x;
  if (t < 64) { s_umin[t] = 64; s_umax[t] = -1; s_nmin[t] = 64; s_nmax[t] = -1; }
  __syncthreads();
  int wave = t >> 6, lane = t & 63;    // lane = l
  unsigned long long ltmask =
      (lane == 63) ? 0x7fffffffffffffffull : ((1ull << lane) - 1ull);
  for (int i = 0; i < 16; ++i) {
    int b = blockIdx.x * 64 + wave * 16 + i;
    int v = indices[b * 64 + lane];
    unsigned long long m0 = __ballot(v & 1);   // bit l set iff site l has up
    unsigned long long m1 = __ballot(v & 2);
    int eu = __popcll(m0 & ltmask);            // exclusive cumsum at site lane
    int ed = __popcll(m1 & ltmask);
    atomicMin(&s_umin[lane], eu); atomicMax(&s_umax[lane], eu);
    atomicMin(&s_nmin[lane], ed); atomicMax(&s_nmax[lane], ed);
  }
  __syncthreads();
  if (t < 64) {
    atomicMin(&ranges[t], s_umin[t]);
    atomicMax(&ranges[64 + t], s_umax[t]);
    atomicMin(&ranges[128 + t], s_nmin[t]);
    atomicMax(&ranges[192 + t], s_nmax[t]);
  }
}

__global__ __launch_bounds__(256) void seggps_transpose(
    const float* __restrict__ eps, __half* __restrict__ tab,
    const int* __restrict__ ranges) {
  int bid = blockIdx.x;                 // grid = 4 * 2080 (triangular)
  int d = bid / 2080;
  int t = bid % 2080;
  int l = (int)((sqrtf(8.0f * (float)t + 1.0f) - 1.0f) * 0.5f);
  while ((l + 1) * (l + 2) / 2 <= t) ++l;   // fix fp rounding
  while (l * (l + 1) / 2 > t) --l;
  int u = t - l * (l + 1) / 2;

  int umin = ranges[l], umax = ranges[64 + l];
  if (u < umin || u > umax) return;     // no batch visits this u at site l
  int nmin = ranges[128 + l], nmax = ranges[192 + l];  // nmax <= l always

  int lane = threadIdx.x & 63;          // n on load, m on store
  int wave = threadIdx.x >> 6;          // 4 waves

  __shared__ float tile[64][65];        // [m][n]

  // load: coalesced along n (stride 1 in eps); nontemporal (no reuse,
  // eps = 277MB > L3)
  const float* src = eps + ((size_t)(d * 64) * 64 + l) * 4225 + u * 65;
  if (lane >= nmin && lane <= nmax) {
#pragma unroll 4
    for (int m = wave; m < 64; m += 4) {
      tile[m][lane] = __builtin_nontemporal_load(&src[(size_t)m * 270400 + lane]);
    }
  }
  __syncthreads();

  // store: coalesced along m (128B contiguous per wave)
  int Pl = l * (l + 1) * (2 * l + 1) / 6;
  __half* dst = tab + (size_t)(Pl + u * (l + 1)) * 256 + d * 64 + lane;
  for (int n = nmin + wave; n <= nmax; n += 4) {
    dst[n * 256] = __float2half(tile[lane][n]);
  }
}

// R5 main: 4 batches per wave. Lane layout: g = lane>>4 selects the batch,
// Lm = lane&15 selects an m-quad (m = 4*Lm .. 4*Lm+3, ushort4 = 8B load,
// 16 lanes x 8B = one 128B line per batch-group per site). Indices of the
// 4 batches are packed 2 bits each into one int -> one __shfl per site.
__global__ __launch_bounds__(256, 4) void seggps_main(
    const int* __restrict__ indices, const __half* __restrict__ tab,
    float* __restrict__ out) {
  int wave = threadIdx.x >> 6;
  int lane = threadIdx.x & 63;
  int g = lane >> 4;                    // batch subgroup 0..3
  int Lm = lane & 15;                   // m-quad index
  int b0 = (blockIdx.x * 4 + wave) * 4; // this wave handles b0 .. b0+3

  int ipk = indices[(b0 + 0) * 64 + lane]
          | (indices[(b0 + 1) * 64 + lane] << 2)
          | (indices[(b0 + 2) * 64 + lane] << 4)
          | (indices[(b0 + 3) * 64 + lane] << 6);

  float p0 = 1.f, p1 = 1.f, p2 = 1.f, p3 = 1.f;
  int up = 0, dn = 0;                   // this lane's batch's counters
  int Pl = 0;                           // l(l+1)(2l+1)/6, built incrementally
  int mbase = Lm * 4;
#pragma unroll 16
  for (int l = 0; l < 64; ++l) {
    int s = __shfl(ipk, l, 64);
    int v = (s >> (2 * g)) & 3;
    int o = (Pl + up * (l + 1) + dn) * 256 + v * 64 + mbase;
    ushort4 q = *reinterpret_cast<const ushort4*>(tab + o);  // 8B, aligned
    p0 *= __half2float(__ushort_as_half(q.x));
    p1 *= __half2float(__ushort_as_half(q.y));
    p2 *= __half2float(__ushort_as_half(q.z));
    p3 *= __half2float(__ushort_as_half(q.w));
    up += v & 1;
    dn += (v >> 1) & 1;
    Pl += (l + 1) * (l + 1);
  }
  // p0..p3 are products for four DIFFERENT m -> sum, then reduce over the
  // 16-lane group (width=16 keeps the shuffle inside the group).
  float r = (p0 + p1) + (p2 + p3);
#pragma unroll
  for (int s = 8; s; s >>= 1) r += __shfl_down(r, s, 16);
  if (Lm == 0) out[b0 + g] = r;
}

// Fallback if workspace is too small: gather straight from eps.
__global__ __launch_bounds__(256) void seggps_direct(
    const int* __restrict__ indices, const float* __restrict__ eps,
    float* __restrict__ out) {
  int wave = threadIdx.x >> 6;
  int lane = threadIdx.x & 63;          // lane = m
  int b = blockIdx.x * 4 + wave;

  int myidx = indices[b * 64 + lane];

  float p0 = 1.f, p1 = 1.f, p2 = 1.f, p3 = 1.f;
  int up = 0, dn = 0;
#pragma unroll 8
  for (int l = 0; l < 64; ++l) {
    int v = __shfl(myidx, l, 64);
    size_t off = ((size_t)((v * 64 + lane) * 64 + l)) * 4225 + up * 65 + dn;
    float e = eps[off];
    if ((l & 3) == 0)      p0 *= e;
    else if ((l & 3) == 1) p1 *= e;
    else if ((l & 3) == 2) p2 *= e;
    else                   p3 *= e;
    up += v & 1;
    dn += (v >> 1) & 1;
  }
  float p = (p0 * p1) * (p2 * p3);
#pragma unroll
  for (int s = 32; s; s >>= 1) p += __shfl_down(p, s, 64);
  if (lane == 0) out[b] = p;
}

extern "C" void kernel_launch(void* const* d_in, const int* in_sizes, int n_in,
                              void* d_out, int out_size, void* d_ws, size_t ws_size,
                              hipStream_t stream) {
  const int* indices = (const int*)d_in[0];   // (8192, 64) int
  const float* eps   = (const float*)d_in[1]; // (4, 64, 64, 65, 65) f32
  float* out = (float*)d_out;                 // (8192,) f32

  if (ws_size >= TAB_HALF_BYTES + 1024) {
    __half* tab = (__half*)d_ws;
    int* ranges = (int*)((char*)d_ws + TAB_HALF_BYTES);  // 256 ints
    hipLaunchKernelGGL(seggps_init, dim3(1), dim3(256), 0, stream, ranges);
    hipLaunchKernelGGL(seggps_ranges, dim3(128), dim3(256), 0, stream,
                       indices, ranges);
    hipLaunchKernelGGL(seggps_transpose, dim3(4 * 2080), dim3(256), 0, stream,
                       eps, tab, ranges);
    hipLaunchKernelGGL(seggps_main, dim3(8192 / 16), dim3(256), 0, stream,
                       indices, tab, out);
  } else {
    hipLaunchKernelGGL(seggps_direct, dim3(8192 / 4), dim3(256), 0, stream,
                       indices, eps, out);
  }
}